// Round 16
// baseline (54.002 us; speedup 1.0000x reference)
//
#include <hip/hip_runtime.h>

// Problem constants (fixed by reference setup_inputs)
#define NB 32
#define NC 128
#define NH 63
#define NW 63
#define HW 3969          // 63*63
#define OH 30            // (63-5)/2+1
#define SEGC 11          // cols per segment: tiles 4s..4s+3 -> x = 8s .. 8s+10
#define RING 9           // LDS row ring (rows mod 9)
#define RPOS (RING*SEGC) // 99 ring positions
#define NBLK 512         // 32 b x 8 col-segs x 2 half-columns

typedef _Float16 half2_t __attribute__((ext_vector_type(2)));
__device__ __forceinline__ half2_t u2h(unsigned u) { return __builtin_bit_cast(half2_t, u); }
__device__ __forceinline__ unsigned h2u(half2_t h) { return __builtin_bit_cast(unsigned, h); }

__device__ __forceinline__ float dot2(unsigned a, unsigned b, float c) {
#if __has_builtin(__builtin_amdgcn_fdot2)
    return __builtin_amdgcn_fdot2(u2h(a), u2h(b), c, false);
#else
    const half2_t x = u2h(a), y = u2h(b);
    c = fmaf((float)x[0], (float)y[0], c);
    return fmaf((float)x[1], (float)y[1], c);
#endif
}

__device__ __forceinline__ unsigned pk16(float a, float b) {
#if __has_builtin(__builtin_amdgcn_cvt_pkrtz)
    return __builtin_bit_cast(unsigned, __builtin_amdgcn_cvt_pkrtz(a, b));
#else
    const half2_t h = {(_Float16)a, (_Float16)b};
    return h2u(h);
#endif
}

// Block = (b, col-seg s of 4 tiles, half-column hf). Iterates 5 superstrips
// (3 output rows each) over a 9-row LDS ring: stages 9 rows first, then 6 new
// rows/iter -> each row read once per half-column (vertical redundancy 1.05x).
// Band granule swizzle: uint4-granule gl of ring-pos at ((gl+pos)&15), same on
// write and read. Running max per thread across all items/iters; 1 slot/block.
// NOTE: bare launch_bounds -- a min-waves clause collapses the VGPR budget and
// spills (R6: 2.6 GB scratch, R7: 58 MB scratch).
__global__ __launch_bounds__(256) void col_kernel(const float* __restrict__ f,
                                                  float* __restrict__ slots) {
    const int bid = blockIdx.x;
    const int b   = bid >> 4;
    const int s   = (bid >> 1) & 7;       // col-seg: x = 8s + [0, 11)
    const int hf  = bid & 1;              // half-column: superstrips 5hf .. 5hf+4
    const int xlo = 8 * s;
    const int t   = threadIdx.x;

    __shared__ unsigned band[RPOS * 64];  // 25344 B: [ringpos][64 u32 = 128 fp16]
    __shared__ float sinv[RPOS];
    __shared__ unsigned sinvh[RPOS];
    __shared__ uint4 Slh[16][12];         // per-(slot, 12 tiles) S as 8 half2
    __shared__ float wred[4];

    const float* fb = f + (size_t)b * NC * HW;

    // dot-item geometry (independent of iteration): items t and t+256 of 300
    const int it0 = t, it1 = t + 256;
    const int tl0 = it0 / 25, p0 = it0 % 25;
    const int tl1 = it1 / 25, p1 = it1 % 25;
    const int j0 = tl0 >> 2, tc0 = tl0 & 3;
    const int j1 = tl1 >> 2, tc1 = tl1 & 3;
    const bool tv0 = (it0 < 300) && (4 * s + tc0 < 30);
    const bool tv1 = (it1 < 300) && (4 * s + tc1 < 30);

    float mrun = 0.0f;

    #pragma unroll 1
    for (int il = 0; il < 5; ++il) {
        const int i = 5 * hf + il;        // superstrip: rows 6i .. 6i+8
        __syncthreads();                  // prior iter's band readers done
        // ---- stage: pairs of lanes (pos, channel-half) ----
        const int npos = (il == 0) ? RPOS : 6 * SEGC;
        if (t < 2 * npos) {
            const int pp = t >> 1, half = t & 1;
            const int k = pp / SEGC, xx = pp % SEGC;
            const int row = (il == 0) ? (6 * i + k) : (6 * i + 3 + k);
            const int pos9 = (row % RING) * SEGC + xx;
            const int x = xlo + xx;
            float ss = 0.0f;
            #pragma unroll
            for (int cb = 0; cb < 4; ++cb) {
                unsigned u[8] = {0u, 0u, 0u, 0u, 0u, 0u, 0u, 0u};
                if (x < NW) {
                    const float* gp = fb + (half * 64 + cb * 16) * HW + row * NW + x;
                    float v[16];
                    #pragma unroll
                    for (int k2 = 0; k2 < 16; ++k2) v[k2] = gp[k2 * HW];
                    #pragma unroll
                    for (int k2 = 0; k2 < 16; ++k2) ss = fmaf(v[k2], v[k2], ss);
                    #pragma unroll
                    for (int jq = 0; jq < 8; ++jq) u[jq] = pk16(v[2 * jq], v[2 * jq + 1]);
                }
                const int g0 = half * 8 + cb * 2;
                *(uint4*)&band[pos9 * 64 + (((g0 + pos9) & 15) << 2)] =
                    make_uint4(u[0], u[1], u[2], u[3]);
                *(uint4*)&band[pos9 * 64 + (((g0 + 1 + pos9) & 15) << 2)] =
                    make_uint4(u[4], u[5], u[6], u[7]);
            }
            const float tot = ss + __shfl_xor(ss, 1);   // halves are adjacent lanes
            if (half == 0) {
                const float inv = (tot > 0.0f) ? rsqrtf(tot) : 0.0f;
                sinv[pos9] = inv;
                sinvh[pos9] = pk16(inv, inv);
            }
        }
        __syncthreads();                  // band + sinv ready
        // ---- S-phase: 192 threads = 12 tiles x 16 slots ----
        if (t < 192) {
            const int tl = t >> 4, slot = t & 15;
            const int j = tl >> 2, tc = tl & 3;
            half2_t s0 = u2h(0u), s1 = u2h(0u), s2 = u2h(0u), s3 = u2h(0u);
            #pragma unroll
            for (int pr = 0; pr < 5; ++pr) {
                const int pos_r = ((6 * i + 2 * j + pr) % RING) * SEGC + 2 * tc;
                #pragma unroll
                for (int pc = 0; pc < 5; ++pc) {
                    const int pos = pos_r + pc;
                    const uint4 v = *(const uint4*)&band[pos * 64 + (((slot + pos) & 15) << 2)];
                    const half2_t iv = u2h(sinvh[pos]);
                    s0 = u2h(v.x) * iv + s0;
                    s1 = u2h(v.y) * iv + s1;
                    s2 = u2h(v.z) * iv + s2;
                    s3 = u2h(v.w) * iv + s3;
                }
            }
            Slh[slot][tl] = make_uint4(h2u(s0), h2u(s1), h2u(s2), h2u(s3));
        }
        __syncthreads();                  // S ready
        // ---- dots: items t and t+256 of 12 tiles x 25 ----
        if (tv0) {
            const int pos = ((6 * i + 2 * j0 + p0 / 5) % RING) * SEGC + 2 * tc0 + p0 % 5;
            float acc = 0.0f;
            #pragma unroll
            for (int slot = 0; slot < 16; ++slot) {
                const uint4 sv = Slh[slot][tl0];
                const uint4 v  = *(const uint4*)&band[pos * 64 + (((slot + pos) & 15) << 2)];
                acc = dot2(v.x, sv.x, acc);
                acc = dot2(v.y, sv.y, acc);
                acc = dot2(v.z, sv.z, acc);
                acc = dot2(v.w, sv.w, acc);
            }
            mrun = fmaxf(mrun, 1.0f - acc * sinv[pos] * 0.04f);
        }
        if (tv1) {
            const int pos = ((6 * i + 2 * j1 + p1 / 5) % RING) * SEGC + 2 * tc1 + p1 % 5;
            float acc = 0.0f;
            #pragma unroll
            for (int slot = 0; slot < 16; ++slot) {
                const uint4 sv = Slh[slot][tl1];
                const uint4 v  = *(const uint4*)&band[pos * 64 + (((slot + pos) & 15) << 2)];
                acc = dot2(v.x, sv.x, acc);
                acc = dot2(v.y, sv.y, acc);
                acc = dot2(v.z, sv.z, acc);
                acc = dot2(v.w, sv.w, acc);
            }
            mrun = fmaxf(mrun, 1.0f - acc * sinv[pos] * 0.04f);
        }
    }

    // ---- epilogue: block max (mrun >= 0 after fmax with 0 init), 1 slot ----
    mrun = fmaxf(mrun, 0.0f);
    #pragma unroll
    for (int off = 1; off < 64; off <<= 1) mrun = fmaxf(mrun, __shfl_xor(mrun, off));
    if ((t & 63) == 0) wred[t >> 6] = mrun;
    __syncthreads();
    if (t == 0)
        slots[bid] = fmaxf(fmaxf(wred[0], wred[1]), fmaxf(wred[2], wred[3]));
}

// ---------------- finalize: 512 slots -> loss ----------------
__global__ __launch_bounds__(256) void finalize(const float* __restrict__ slots,
                                                const int* __restrict__ label,
                                                float* __restrict__ out) {
    const int t = threadIdx.x;
    __shared__ float bmax[32];
    const int b = t >> 3, k = t & 7;      // 8 lanes per b, 16 slots each
    float m = fmaxf(slots[b * 16 + k], slots[b * 16 + 8 + k]);
    m = fmaxf(m, __shfl_xor(m, 1));
    m = fmaxf(m, __shfl_xor(m, 2));
    m = fmaxf(m, __shfl_xor(m, 4));
    if (k == 0) bmax[b] = m;
    __syncthreads();
    if (t == 0) {
        float fs = 0.0f, rs = 0.0f, fc = 0.0f, rc = 0.0f;
        for (int b2 = 0; b2 < NB; ++b2) {
            const float tb  = bmax[b2];
            const float lbv = (float)label[b2];
            fs += tb * lbv;          fc += lbv;
            rs += tb * (1.0f - lbv); rc += (1.0f - lbv);
        }
        const float loss = 1.0f - fs / fc + rs / rc;
        out[0] = fmaxf(loss, 0.0f);
    }
}

extern "C" void kernel_launch(void* const* d_in, const int* in_sizes, int n_in,
                              void* d_out, int out_size, void* d_ws, size_t ws_size,
                              hipStream_t stream) {
    const float* feature = (const float*)d_in[0];
    const int* label     = (const int*)d_in[1];
    float* out   = (float*)d_out;
    float* slots = (float*)d_ws;   // 512 floats, fully rewritten each launch

    col_kernel<<<NBLK, 256, 0, stream>>>(feature, slots);
    finalize<<<1, 256, 0, stream>>>(slots, label, out);
}

// Round 17
// 33.048 us; speedup vs baseline: 1.6340x; 1.6340x over previous
//
#include <hip/hip_runtime.h>

// Problem constants (fixed by reference setup_inputs)
#define NB 32
#define NC 128
#define NH 63
#define NW 63
#define HW 3969          // 63*63
#define OH 30            // (63-5)/2+1
#define SEGW 19          // band cols per segment (tiles 8g..8g+7 -> cols 16g..16g+18)
#define NROW 9           // 3 strips: rows y0..y0+8
#define POSN (NROW*SEGW) // 171
#define NSST 10          // superstrips per b (30 = 3*10)
#define NSEG 4
#define NBLK (NB*NSST*NSEG)  // 1280

typedef _Float16 half2_t __attribute__((ext_vector_type(2)));
__device__ __forceinline__ half2_t u2h(unsigned u) { return __builtin_bit_cast(half2_t, u); }
__device__ __forceinline__ unsigned h2u(half2_t h) { return __builtin_bit_cast(unsigned, h); }

__device__ __forceinline__ float dot2(unsigned a, unsigned b, float c) {
#if __has_builtin(__builtin_amdgcn_fdot2)
    return __builtin_amdgcn_fdot2(u2h(a), u2h(b), c, false);
#else
    const half2_t x = u2h(a), y = u2h(b);
    c = fmaf((float)x[0], (float)y[0], c);
    return fmaf((float)x[1], (float)y[1], c);
#endif
}

__device__ __forceinline__ unsigned pk16(float a, float b) {
#if __has_builtin(__builtin_amdgcn_cvt_pkrtz)
    return __builtin_bit_cast(unsigned, __builtin_amdgcn_cvt_pkrtz(a, b));
#else
    const half2_t h = {(_Float16)a, (_Float16)b};
    return h2u(h);
#endif
}

// One block per (b, 3-strip superstrip, 8-tile segment) -- R15 champion geometry.
// Stage: one thread owns one position's 128 channels (adjacent lanes = adjacent x
// -> coalesced; R16 taught us breaking this quadruples HBM fetch). NEW this round:
// 2-deep register prefetch (vc/vn) so chunk ch+1's global loads issue before
// chunk ch's fma/pk16/LDS writes -- hides the 8-chunk latency chain (T14).
// Band granule swizzle: uint4-granule gl of pos at ((gl+pos)&15), same on write
// and read (both-sides rule).
// NOTE: bare launch_bounds -- a min-waves clause collapses the VGPR budget and
// spills (R6: 2.6 GB scratch, R7: 58 MB scratch).
__global__ __launch_bounds__(256) void seg_fused(const float* __restrict__ f,
                                                 float* __restrict__ slots) {
    // XCD-chunked swizzle (bijective: 1280 = 8*160).
    const int lb  = (blockIdx.x & 7) * (NBLK / 8) + (blockIdx.x >> 3);
    const int b   = lb / (NSST * NSEG);
    const int rem = lb % (NSST * NSEG);
    const int sst = rem >> 2, g = rem & 3;
    const int y0 = 6 * sst, xlo = 16 * g;
    const int t = threadIdx.x;

    __shared__ unsigned band[POSN * 64];   // 43776 B: [pos][64 uints = 128 fp16]
    __shared__ float sinv[POSN];
    __shared__ unsigned sinvh[POSN];
    __shared__ uint4 Slh[16][24];          // 6144 B: per-(slot, tile) S as 8 half2
    __shared__ float wmax[3][4];

    // ---- stage: t<171 owns position t (all 128 channels), 2-deep prefetch ----
    if (t < POSN) {
        const int r = t / SEGW, xx = t % SEGW;
        const int x = xlo + xx;
        float inv = 0.0f;
        if (x < NW) {
            const float* gp = f + (size_t)b * NC * HW + (size_t)(y0 + r) * NW + x;
            float ss = 0.0f;
            float vc[16], vn[16];
            #pragma unroll
            for (int k = 0; k < 16; ++k) vc[k] = gp[(size_t)k * HW];
            #pragma unroll
            for (int ch = 0; ch < 8; ++ch) {
                if (ch < 7) {
                    #pragma unroll
                    for (int k = 0; k < 16; ++k)
                        vn[k] = gp[(size_t)((ch + 1) * 16 + k) * HW];
                }
                #pragma unroll
                for (int k = 0; k < 16; ++k) ss = fmaf(vc[k], vc[k], ss);
                unsigned u[8];
                #pragma unroll
                for (int j = 0; j < 8; ++j) u[j] = pk16(vc[2 * j], vc[2 * j + 1]);
                *(uint4*)&band[t * 64 + (((2 * ch     + t) & 15) << 2)] =
                    make_uint4(u[0], u[1], u[2], u[3]);
                *(uint4*)&band[t * 64 + (((2 * ch + 1 + t) & 15) << 2)] =
                    make_uint4(u[4], u[5], u[6], u[7]);
                #pragma unroll
                for (int k = 0; k < 16; ++k) vc[k] = vn[k];
            }
            inv = (ss > 0.0f) ? rsqrtf(ss) : 0.0f;
        } else {
            #pragma unroll
            for (int j = 0; j < 16; ++j)
                *(uint4*)&band[t * 64 + (((j + t) & 15) << 2)] = make_uint4(0u, 0u, 0u, 0u);
        }
        sinv[t] = inv;
        const half2_t i2 = {(_Float16)inv, (_Float16)inv};
        sinvh[t] = h2u(i2);
    }
    __syncthreads();

    // ---- S-phase: 384 items (24 tiles x 16 slots); thread t does t and t+256 ----
    #pragma unroll
    for (int jj = 0; jj < 2; ++jj) {
        const int i = t + jj * 256;
        if (i < 384) {
            const int tl = i >> 4, slot = i & 15;
            const int s_ = tl >> 3, txx = tl & 7;
            half2_t s0 = u2h(0u), s1 = u2h(0u), s2 = u2h(0u), s3 = u2h(0u);
            #pragma unroll
            for (int pr = 0; pr < 5; ++pr)
                #pragma unroll
                for (int pc = 0; pc < 5; ++pc) {
                    const int pos = (2 * s_ + pr) * SEGW + 2 * txx + pc;
                    const uint4 v = *(const uint4*)&band[pos * 64 + (((slot + pos) & 15) << 2)];
                    const half2_t iv = u2h(sinvh[pos]);
                    s0 = u2h(v.x) * iv + s0;
                    s1 = u2h(v.y) * iv + s1;
                    s2 = u2h(v.z) * iv + s2;
                    s3 = u2h(v.w) * iv + s3;
                }
            Slh[slot][tl] = make_uint4(h2u(s0), h2u(s1), h2u(s2), h2u(s3));
        }
    }
    __syncthreads();

    // ---- dots: t<200 -> items {t, t+200, t+400} = strips {0,1,2} at pos+38j ----
    float m[3] = {0.0f, 0.0f, 0.0f};
    if (t < 200) {
        const int txx = t / 25, p = t % 25;
        if (8 * g + txx < OH) {
            const int pos0 = (p / 5) * SEGW + 2 * txx + (p % 5);
            #pragma unroll
            for (int j = 0; j < 3; ++j) {
                const int pos = pos0 + 2 * SEGW * j;
                const int tl  = 8 * j + txx;
                float acc = 0.0f;
                #pragma unroll
                for (int slot = 0; slot < 16; ++slot) {
                    const uint4 sv = Slh[slot][tl];
                    const uint4 v  = *(const uint4*)&band[pos * 64 + (((slot + pos) & 15) << 2)];
                    acc = dot2(v.x, sv.x, acc);
                    acc = dot2(v.y, sv.y, acc);
                    acc = dot2(v.z, sv.z, acc);
                    acc = dot2(v.w, sv.w, acc);
                }
                m[j] = fmaxf(0.0f, 1.0f - acc * sinv[pos] * 0.04f);
            }
        }
    }
    #pragma unroll
    for (int off = 1; off < 64; off <<= 1) {
        m[0] = fmaxf(m[0], __shfl_xor(m[0], off));
        m[1] = fmaxf(m[1], __shfl_xor(m[1], off));
        m[2] = fmaxf(m[2], __shfl_xor(m[2], off));
    }
    if ((t & 63) == 0) {
        wmax[0][t >> 6] = m[0];
        wmax[1][t >> 6] = m[1];
        wmax[2][t >> 6] = m[2];
    }
    __syncthreads();
    if (t < 3) {
        const float mm = fmaxf(fmaxf(wmax[t][0], wmax[t][1]),
                               fmaxf(wmax[t][2], wmax[t][3]));
        // slot layout [b][oi][g], oi = 3*sst + t
        slots[((b * OH) + 3 * sst + t) * 4 + g] = mm;
    }
}

// ---------------- finalize: 3840 slots -> loss ----------------
__global__ __launch_bounds__(128) void finalize(const float* __restrict__ slots,
                                                const int* __restrict__ label,
                                                float* __restrict__ out) {
    const int t = threadIdx.x;
    __shared__ float bmax[32];
    const int b = t >> 2, j = t & 3;          // 4 threads per b, 120 slots each
    float m = 0.0f;
    for (int i = j; i < 120; i += 4) m = fmaxf(m, slots[b * 120 + i]);
    m = fmaxf(m, __shfl_xor(m, 1));
    m = fmaxf(m, __shfl_xor(m, 2));
    if (j == 0) bmax[b] = m;
    __syncthreads();
    if (t == 0) {
        float fs = 0.0f, rs = 0.0f, fc = 0.0f, rc = 0.0f;
        for (int b2 = 0; b2 < NB; ++b2) {
            const float tb  = bmax[b2];
            const float lbv = (float)label[b2];
            fs += tb * lbv;          fc += lbv;
            rs += tb * (1.0f - lbv); rc += (1.0f - lbv);
        }
        const float loss = 1.0f - fs / fc + rs / rc;
        out[0] = fmaxf(loss, 0.0f);
    }
}

extern "C" void kernel_launch(void* const* d_in, const int* in_sizes, int n_in,
                              void* d_out, int out_size, void* d_ws, size_t ws_size,
                              hipStream_t stream) {
    const float* feature = (const float*)d_in[0];
    const int* label     = (const int*)d_in[1];
    float* out   = (float*)d_out;
    float* slots = (float*)d_ws;   // 3840 floats, fully rewritten each launch

    seg_fused<<<NBLK, 256, 0, stream>>>(feature, slots);
    finalize<<<1, 128, 0, stream>>>(slots, label, out);
}

// Round 18
// 29.050 us; speedup vs baseline: 1.8589x; 1.1376x over previous
//
#include <hip/hip_runtime.h>

// Problem constants (fixed by reference setup_inputs)
#define NB 32
#define NC 128
#define NH 63
#define NW 63
#define HW 3969          // 63*63
#define OH 30            // (63-5)/2+1
#define SEGW 13          // 13x13 block: 5 tiles x 5 strips, advance 10 in both dims
#define NROW 13
#define POSN (NROW*SEGW) // 169
#define NSST 6           // row superstrips per b (30 = 6*5)
#define NCS 6            // col segments per b (30 = 6*5)
#define NBLK (NB*NSST*NCS)  // 1152
// 63 = 6*10 + 3 and 30 = 6*5 exactly -> no edge masking anywhere.

typedef _Float16 half2_t __attribute__((ext_vector_type(2)));
__device__ __forceinline__ half2_t u2h(unsigned u) { return __builtin_bit_cast(half2_t, u); }
__device__ __forceinline__ unsigned h2u(half2_t h) { return __builtin_bit_cast(unsigned, h); }

__device__ __forceinline__ float dot2(unsigned a, unsigned b, float c) {
#if __has_builtin(__builtin_amdgcn_fdot2)
    return __builtin_amdgcn_fdot2(u2h(a), u2h(b), c, false);
#else
    const half2_t x = u2h(a), y = u2h(b);
    c = fmaf((float)x[0], (float)y[0], c);
    return fmaf((float)x[1], (float)y[1], c);
#endif
}

__device__ __forceinline__ unsigned pk16(float a, float b) {
#if __has_builtin(__builtin_amdgcn_cvt_pkrtz)
    return __builtin_bit_cast(unsigned, __builtin_amdgcn_cvt_pkrtz(a, b));
#else
    const half2_t h = {(_Float16)a, (_Float16)b};
    return h2u(h);
#endif
}

// One block per (b, 13-row superstrip, 13-col segment): 25 tiles, redundancy
// 169/100 = 1.69x (vs 1.78x for 9x19). Stage: one thread owns one position's
// 128 channels (adjacent lanes = adjacent x -> coalesced; R16: breaking this
// quadruples HBM fetch), 2-deep register prefetch (T14). Band granule swizzle:
// uint4-granule gl of pos at ((gl+pos)&15), same on write and read.
// NOTE: bare launch_bounds -- a min-waves clause collapses the VGPR budget and
// spills (R6: 2.6 GB scratch, R7: 58 MB scratch).
__global__ __launch_bounds__(256) void seg_fused(const float* __restrict__ f,
                                                 float* __restrict__ slots) {
    // XCD-chunked swizzle (bijective: 1152 = 8*144).
    const int lb  = (blockIdx.x & 7) * (NBLK / 8) + (blockIdx.x >> 3);
    const int b   = lb / (NSST * NCS);
    const int rem = lb % (NSST * NCS);
    const int sst = rem / NCS, cs = rem % NCS;
    const int y0 = 10 * sst, xlo = 10 * cs;
    const int t = threadIdx.x;

    __shared__ unsigned band[POSN * 64];   // 43264 B: [pos][64 uints = 128 fp16]
    __shared__ float sinv[POSN];
    __shared__ unsigned sinvh[POSN];
    __shared__ uint4 Slh[16][25];          // 6400 B: per-(slot, tile) S as 8 half2
    __shared__ float wmax[4];

    // ---- stage: t<169 owns position t (all 128 channels), 2-deep prefetch ----
    if (t < POSN) {
        const int r = t / SEGW, xx = t % SEGW;
        const float* gp = f + (size_t)b * NC * HW + (size_t)(y0 + r) * NW + xlo + xx;
        float ss = 0.0f;
        float vc[16], vn[16];
        #pragma unroll
        for (int k = 0; k < 16; ++k) vc[k] = gp[(size_t)k * HW];
        #pragma unroll
        for (int ch = 0; ch < 8; ++ch) {
            if (ch < 7) {
                #pragma unroll
                for (int k = 0; k < 16; ++k)
                    vn[k] = gp[(size_t)((ch + 1) * 16 + k) * HW];
            }
            #pragma unroll
            for (int k = 0; k < 16; ++k) ss = fmaf(vc[k], vc[k], ss);
            unsigned u[8];
            #pragma unroll
            for (int j = 0; j < 8; ++j) u[j] = pk16(vc[2 * j], vc[2 * j + 1]);
            *(uint4*)&band[t * 64 + (((2 * ch     + t) & 15) << 2)] =
                make_uint4(u[0], u[1], u[2], u[3]);
            *(uint4*)&band[t * 64 + (((2 * ch + 1 + t) & 15) << 2)] =
                make_uint4(u[4], u[5], u[6], u[7]);
            #pragma unroll
            for (int k = 0; k < 16; ++k) vc[k] = vn[k];
        }
        const float inv = (ss > 0.0f) ? rsqrtf(ss) : 0.0f;
        sinv[t] = inv;
        const half2_t i2 = {(_Float16)inv, (_Float16)inv};
        sinvh[t] = h2u(i2);
    }
    __syncthreads();

    // ---- S-phase: 400 items (25 tiles x 16 slots); thread t does t and t+256 ----
    #pragma unroll
    for (int jj = 0; jj < 2; ++jj) {
        const int i = t + jj * 256;
        if (i < 400) {
            const int tl = i >> 4, slot = i & 15;
            const int j = tl / 5, tc = tl % 5;   // strip j, tile-col tc
            half2_t s0 = u2h(0u), s1 = u2h(0u), s2 = u2h(0u), s3 = u2h(0u);
            #pragma unroll
            for (int pr = 0; pr < 5; ++pr)
                #pragma unroll
                for (int pc = 0; pc < 5; ++pc) {
                    const int pos = (2 * j + pr) * SEGW + 2 * tc + pc;
                    const uint4 v = *(const uint4*)&band[pos * 64 + (((slot + pos) & 15) << 2)];
                    const half2_t iv = u2h(sinvh[pos]);
                    s0 = u2h(v.x) * iv + s0;
                    s1 = u2h(v.y) * iv + s1;
                    s2 = u2h(v.z) * iv + s2;
                    s3 = u2h(v.w) * iv + s3;
                }
            Slh[slot][tl] = make_uint4(h2u(s0), h2u(s1), h2u(s2), h2u(s3));
        }
    }
    __syncthreads();

    // ---- dots: 625 items (25 tiles x 25 p); t<250 does {t, t+250} and t<125 +500 ----
    float m = 0.0f;
    #pragma unroll
    for (int jj = 0; jj < 3; ++jj) {
        const int it = t + jj * 250;
        if (t < 250 && it < 625) {
            const int tl = it / 25, p = it % 25;
            const int j = tl / 5, tc = tl % 5;
            const int pos = (2 * j + p / 5) * SEGW + 2 * tc + (p % 5);
            float acc = 0.0f;
            #pragma unroll
            for (int slot = 0; slot < 16; ++slot) {
                const uint4 sv = Slh[slot][tl];
                const uint4 v  = *(const uint4*)&band[pos * 64 + (((slot + pos) & 15) << 2)];
                acc = dot2(v.x, sv.x, acc);
                acc = dot2(v.y, sv.y, acc);
                acc = dot2(v.z, sv.z, acc);
                acc = dot2(v.w, sv.w, acc);
            }
            m = fmaxf(m, 1.0f - acc * sinv[pos] * 0.04f);
        }
    }
    // ---- block max (m >= 0 via init 0), one slot per block ----
    #pragma unroll
    for (int off = 1; off < 64; off <<= 1) m = fmaxf(m, __shfl_xor(m, off));
    if ((t & 63) == 0) wmax[t >> 6] = m;
    __syncthreads();
    if (t == 0)
        slots[lb] = fmaxf(fmaxf(wmax[0], wmax[1]), fmaxf(wmax[2], wmax[3]));
}

// ---------------- finalize: 1152 slots (36 per b) -> loss ----------------
__global__ __launch_bounds__(256) void finalize(const float* __restrict__ slots,
                                                const int* __restrict__ label,
                                                float* __restrict__ out) {
    const int t = threadIdx.x;
    __shared__ float bmax[32];
    const int b = t >> 3, k = t & 7;      // 8 lanes per b, 36 slots each
    float m = 0.0f;
    for (int i = k; i < 36; i += 8) m = fmaxf(m, slots[b * 36 + i]);
    m = fmaxf(m, __shfl_xor(m, 1));
    m = fmaxf(m, __shfl_xor(m, 2));
    m = fmaxf(m, __shfl_xor(m, 4));
    if (k == 0) bmax[b] = m;
    __syncthreads();
    if (t == 0) {
        float fs = 0.0f, rs = 0.0f, fc = 0.0f, rc = 0.0f;
        for (int b2 = 0; b2 < NB; ++b2) {
            const float tb  = bmax[b2];
            const float lbv = (float)label[b2];
            fs += tb * lbv;          fc += lbv;
            rs += tb * (1.0f - lbv); rc += (1.0f - lbv);
        }
        const float loss = 1.0f - fs / fc + rs / rc;
        out[0] = fmaxf(loss, 0.0f);
    }
}

extern "C" void kernel_launch(void* const* d_in, const int* in_sizes, int n_in,
                              void* d_out, int out_size, void* d_ws, size_t ws_size,
                              hipStream_t stream) {
    const float* feature = (const float*)d_in[0];
    const int* label     = (const int*)d_in[1];
    float* out   = (float*)d_out;
    float* slots = (float*)d_ws;   // 1152 floats, fully rewritten each launch

    seg_fused<<<NBLK, 256, 0, stream>>>(feature, slots);
    finalize<<<1, 256, 0, stream>>>(slots, label, out);
}